// Round 2
// baseline (937.727 us; speedup 1.0000x reference)
//
#include <hip/hip_runtime.h>

typedef __attribute__((ext_vector_type(4))) float f32x4;
typedef __attribute__((ext_vector_type(8))) short short8;
typedef __attribute__((ext_vector_type(4))) unsigned short u16x4;
typedef unsigned short u16;

#define GLD(g, l) __builtin_amdgcn_global_load_lds((const __attribute__((address_space(1))) unsigned int*)(g), (__attribute__((address_space(3))) unsigned int*)(l), 16, 0, 0)

__device__ __forceinline__ u16 f2bf(float f){
  union { float f; unsigned u; } c; c.f = f;
  unsigned r = c.u + 0x7FFFu + ((c.u >> 16) & 1u);
  return (u16)(r >> 16);
}

__device__ __forceinline__ float gelu_tanh(float x){
  float a = 0.7978845608028654f * (x + 0.044715f * x * x * x);
  float t = 1.0f - 2.0f / (__expf(2.0f * a) + 1.0f);
  return 0.5f * x * (1.0f + t);
}

// ---------------- cast kernels ----------------
__global__ __launch_bounds__(256) void cast_flat_k(const float* __restrict__ s, u16* __restrict__ d, int n4){
  int i = blockIdx.x * 256 + threadIdx.x;
  int str = gridDim.x * 256;
  for (; i < n4; i += str){
    f32x4 v = ((const f32x4*)s)[i];
    u16x4 o; o[0]=f2bf(v[0]); o[1]=f2bf(v[1]); o[2]=f2bf(v[2]); o[3]=f2bf(v[3]);
    ((u16x4*)d)[i] = o;
  }
}

// B1 [E=8, F=8192, R=8] -> B1c [F, 64]: B1c[f][e*8+r] = B1[e][f][r]
__global__ __launch_bounds__(256) void cast_b1c_k(const float* __restrict__ B1, u16* __restrict__ B1c){
  int i = blockIdx.x * 256 + threadIdx.x;   // 0..524287
  int f = i >> 6, er = i & 63, e = er >> 3, r = er & 7;
  B1c[i] = f2bf(B1[(size_t)e * 65536 + (size_t)f * 8 + r]);
}

// B2 [E=8, D=2048, R=8] -> B2c [D, 64]: B2c[d][e*8+r] = B2[e][d][r]
__global__ __launch_bounds__(256) void cast_b2c_k(const float* __restrict__ B2, u16* __restrict__ B2c){
  int i = blockIdx.x * 256 + threadIdx.x;   // 0..131071
  int d_ = i >> 6, er = i & 63, e = er >> 3, r = er & 7;
  B2c[i] = f2bf(B2[(size_t)e * 16384 + (size_t)d_ * 8 + r]);
}

// ---------------- router (+ x cast + selected u1 -> z1) ----------------
__global__ __launch_bounds__(256) void router_k(
    const float* __restrict__ x, const float* __restrict__ Wr, const float* __restrict__ br,
    const float* __restrict__ A1, u16* __restrict__ xb,
    u16* __restrict__ z1s0, u16* __restrict__ z1d,
    float* __restrict__ rw, int* __restrict__ ridx)
{
  const int t = threadIdx.x, wid = t >> 6, l = t & 63;
  const int n = blockIdx.x * 4 + wid;
  const float* xr = x + (size_t)n * 2048;
  f32x4 xv[8];
#pragma unroll
  for (int i = 0; i < 8; ++i) xv[i] = *(const f32x4*)(xr + i * 256 + l * 4);
#pragma unroll
  for (int i = 0; i < 8; ++i){
    u16x4 o; o[0]=f2bf(xv[i][0]); o[1]=f2bf(xv[i][1]); o[2]=f2bf(xv[i][2]); o[3]=f2bf(xv[i][3]);
    *(u16x4*)(xb + (size_t)n * 2048 + i * 256 + l * 4) = o;
  }
  float p[8];
#pragma unroll
  for (int e = 0; e < 8; ++e){
    const float* wrow = Wr + (size_t)e * 2048;
    float s = 0.f;
#pragma unroll
    for (int i = 0; i < 8; ++i){
      f32x4 wv = *(const f32x4*)(wrow + i * 256 + l * 4);
      s += xv[i][0]*wv[0] + xv[i][1]*wv[1] + xv[i][2]*wv[2] + xv[i][3]*wv[3];
    }
#pragma unroll
    for (int off = 32; off; off >>= 1) s += __shfl_xor(s, off, 64);
    p[e] = s + br[e];
  }
  float mx = p[0];
#pragma unroll
  for (int e = 1; e < 8; ++e) mx = fmaxf(mx, p[e]);
  float den = 0.f;
#pragma unroll
  for (int e = 0; e < 8; ++e){ p[e] = __expf(p[e] - mx); den += p[e]; }
  float inv = 1.f / den;
#pragma unroll
  for (int e = 0; e < 8; ++e) p[e] *= inv;
  int e0 = 0; float p0 = p[0];
#pragma unroll
  for (int e = 1; e < 8; ++e){ if (p[e] > p0){ p0 = p[e]; e0 = e; } }
  int e1 = (e0 == 0) ? 1 : 0; float p1 = p[(e0 == 0) ? 1 : 0];
#pragma unroll
  for (int e = 0; e < 8; ++e){ if (e != e0 && p[e] > p1){ p1 = p[e]; e1 = e; } }

  float mz0 = 0.f, mz1 = 0.f;
#pragma unroll
  for (int r = 0; r < 8; ++r){
    const float* a1r = A1 + ((size_t)(e0 * 8 + r)) * 2048;
    float s = 0.f;
#pragma unroll
    for (int i = 0; i < 8; ++i){
      f32x4 av = *(const f32x4*)(a1r + i * 256 + l * 4);
      s += xv[i][0]*av[0] + xv[i][1]*av[1] + xv[i][2]*av[2] + xv[i][3]*av[3];
    }
#pragma unroll
    for (int off = 32; off; off >>= 1) s += __shfl_xor(s, off, 64);
    if (l == e0 * 8 + r) mz0 = 2.0f * s;   // SCALING folded
  }
#pragma unroll
  for (int r = 0; r < 8; ++r){
    const float* a1r = A1 + ((size_t)(e1 * 8 + r)) * 2048;
    float s = 0.f;
#pragma unroll
    for (int i = 0; i < 8; ++i){
      f32x4 av = *(const f32x4*)(a1r + i * 256 + l * 4);
      s += xv[i][0]*av[0] + xv[i][1]*av[1] + xv[i][2]*av[2] + xv[i][3]*av[3];
    }
#pragma unroll
    for (int off = 32; off; off >>= 1) s += __shfl_xor(s, off, 64);
    if (l == e1 * 8 + r) mz1 = 2.0f * s;
  }
  z1s0[(size_t)n * 64 + l] = f2bf(mz0);
  z1d [(size_t)n * 64 + l] = f2bf(mz1 - mz0);
  if (l == 0){
    rw[n * 2 + 0] = p0; rw[n * 2 + 1] = p1;
    ridx[n * 2 + 0] = e0; ridx[n * 2 + 1] = e1;
  }
}

// ---------------- fc1 GEMM + lora + gelu -> h0, h1 ----------------
// C tile 128x128, 4 waves (2x2), wave tile 64x64, BK=32, m97 structure.
__global__ __launch_bounds__(256) void gemm_fc1_k(
    const u16* __restrict__ xb, const u16* __restrict__ W1b,
    const u16* __restrict__ B1c, const u16* __restrict__ z1s0, const u16* __restrict__ z1d,
    const float* __restrict__ b1, u16* __restrict__ h0, u16* __restrict__ h1)
{
  __shared__ __align__(16) short lds[24576];
  short* As = lds;           // [128][32]
  short* Bs = lds + 4096;    // [128][32]
  short* Bl = lds + 8192;    // [128][64]
  short* Zs = lds + 16384;   // [128][64]
  const int t = threadIdx.x, l = t & 63, wid = t >> 6;
  const int wr = wid >> 1, wc = wid & 1;
  const int fq = l >> 4, fr = l & 15;
  const int brow = blockIdx.y * 128, bcol = blockIdx.x * 128;

#pragma unroll
  for (int p = 0; p < 4; ++p){
    int i = p * 256 + t, row = i >> 3, ch = i & 7;
    GLD(B1c + (size_t)(bcol + row) * 64 + ch * 8, (char*)Bl + i * 16);
    GLD(z1s0 + (size_t)(brow + row) * 64 + ch * 8, (char*)Zs + i * 16);
  }

  f32x4 acc[4][4] = {};
  for (int kt = 0; kt < 64; ++kt){
    const int k0 = kt * 32;
#pragma unroll
    for (int p = 0; p < 2; ++p){
      int i = p * 256 + t, row = i >> 2, ch = i & 3;
      GLD(xb  + (size_t)(brow + row) * 2048 + k0 + ch * 8, (char*)As + i * 16);
      GLD(W1b + (size_t)(bcol + row) * 2048 + k0 + ch * 8, (char*)Bs + i * 16);
    }
    __syncthreads();
    short8 a[4], b[4];
#pragma unroll
    for (int m = 0; m < 4; ++m) a[m] = *(const short8*)&As[(wr * 64 + m * 16 + fr) * 32 + fq * 8];
#pragma unroll
    for (int n = 0; n < 4; ++n) b[n] = *(const short8*)&Bs[(wc * 64 + n * 16 + fr) * 32 + fq * 8];
#pragma unroll
    for (int m = 0; m < 4; ++m)
#pragma unroll
      for (int n = 0; n < 4; ++n)
        acc[m][n] = __builtin_amdgcn_mfma_f32_16x16x32_bf16(a[m], b[n], acc[m][n], 0, 0, 0);
    __syncthreads();
  }

#pragma unroll
  for (int n = 0; n < 4; ++n){
    float bv = b1[bcol + wc * 64 + n * 16 + fr];
#pragma unroll
    for (int m = 0; m < 4; ++m)
#pragma unroll
      for (int j = 0; j < 4; ++j) acc[m][n][j] += bv;
  }
  // lora for k=0 (Zs holds z1s0); K=64 contraction in two K=32 steps
#pragma unroll
  for (int kk = 0; kk < 2; ++kk){
    short8 za[4], zb[4];
#pragma unroll
    for (int m = 0; m < 4; ++m) za[m] = *(const short8*)&Zs[(wr * 64 + m * 16 + fr) * 64 + kk * 32 + fq * 8];
#pragma unroll
    for (int n = 0; n < 4; ++n) zb[n] = *(const short8*)&Bl[(wc * 64 + n * 16 + fr) * 64 + kk * 32 + fq * 8];
#pragma unroll
    for (int m = 0; m < 4; ++m)
#pragma unroll
      for (int n = 0; n < 4; ++n)
        acc[m][n] = __builtin_amdgcn_mfma_f32_16x16x32_bf16(za[m], zb[n], acc[m][n], 0, 0, 0);
  }
#pragma unroll
  for (int m = 0; m < 4; ++m)
#pragma unroll
    for (int n = 0; n < 4; ++n)
#pragma unroll
      for (int j = 0; j < 4; ++j){
        int grow = brow + wr * 64 + m * 16 + fq * 4 + j;
        int gcol = bcol + wc * 64 + n * 16 + fr;
        h0[(size_t)grow * 8192 + gcol] = f2bf(gelu_tanh(acc[m][n][j]));
      }
  __syncthreads();
  // restage Zs with z1d = z1(k=1) - z1(k=0); acc += z1d@B1 gives k=1 state
#pragma unroll
  for (int p = 0; p < 4; ++p){
    int i = p * 256 + t, row = i >> 3, ch = i & 7;
    GLD(z1d + (size_t)(brow + row) * 64 + ch * 8, (char*)Zs + i * 16);
  }
  __syncthreads();
#pragma unroll
  for (int kk = 0; kk < 2; ++kk){
    short8 za[4], zb[4];
#pragma unroll
    for (int m = 0; m < 4; ++m) za[m] = *(const short8*)&Zs[(wr * 64 + m * 16 + fr) * 64 + kk * 32 + fq * 8];
#pragma unroll
    for (int n = 0; n < 4; ++n) zb[n] = *(const short8*)&Bl[(wc * 64 + n * 16 + fr) * 64 + kk * 32 + fq * 8];
#pragma unroll
    for (int m = 0; m < 4; ++m)
#pragma unroll
      for (int n = 0; n < 4; ++n)
        acc[m][n] = __builtin_amdgcn_mfma_f32_16x16x32_bf16(za[m], zb[n], acc[m][n], 0, 0, 0);
  }
#pragma unroll
  for (int m = 0; m < 4; ++m)
#pragma unroll
    for (int n = 0; n < 4; ++n)
#pragma unroll
      for (int j = 0; j < 4; ++j){
        int grow = brow + wr * 64 + m * 16 + fq * 4 + j;
        int gcol = bcol + wc * 64 + n * 16 + fr;
        h1[(size_t)grow * 8192 + gcol] = f2bf(gelu_tanh(acc[m][n][j]));
      }
}

// ---------------- u2 = h @ A2_flat^T, split-K into 16 slabs ----------------
__global__ __launch_bounds__(256) void gemm_u2_k(
    const u16* __restrict__ h, const u16* __restrict__ A2b, float* __restrict__ u2p)
{
  __shared__ __align__(16) short lds[6144];
  short* As = lds;          // [128][32]
  short* Bs = lds + 4096;   // [64][32]
  const int t = threadIdx.x, l = t & 63, wid = t >> 6;
  const int fq = l >> 4, fr = l & 15;
  const int bs = blockIdx.x;            // split 0..15
  const int brow = blockIdx.y * 128;
  const int kb = bs * 512;

  f32x4 acc[2][4] = {};
  for (int kt = 0; kt < 16; ++kt){
    const int k0 = kb + kt * 32;
#pragma unroll
    for (int p = 0; p < 2; ++p){
      int i = p * 256 + t, row = i >> 2, ch = i & 3;
      GLD(h + (size_t)(brow + row) * 8192 + k0 + ch * 8, (char*)As + i * 16);
    }
    { int i = t, row = i >> 2, ch = i & 3;
      GLD(A2b + (size_t)row * 8192 + k0 + ch * 8, (char*)Bs + i * 16); }
    __syncthreads();
    short8 a[2], b[4];
#pragma unroll
    for (int m = 0; m < 2; ++m) a[m] = *(const short8*)&As[(wid * 32 + m * 16 + fr) * 32 + fq * 8];
#pragma unroll
    for (int n = 0; n < 4; ++n) b[n] = *(const short8*)&Bs[(n * 16 + fr) * 32 + fq * 8];
#pragma unroll
    for (int m = 0; m < 2; ++m)
#pragma unroll
      for (int n = 0; n < 4; ++n)
        acc[m][n] = __builtin_amdgcn_mfma_f32_16x16x32_bf16(a[m], b[n], acc[m][n], 0, 0, 0);
    __syncthreads();
  }
#pragma unroll
  for (int m = 0; m < 2; ++m)
#pragma unroll
    for (int n = 0; n < 4; ++n)
#pragma unroll
      for (int j = 0; j < 4; ++j){
        int grow = brow + wid * 32 + m * 16 + fq * 4 + j;
        u2p[(size_t)bs * 262144 + (size_t)grow * 64 + n * 16 + fr] = acc[m][n][j];
      }
}

// ---------------- z2 build: sum splits, mask expert, scale ----------------
__global__ __launch_bounds__(256) void zbuild_k(
    const float* __restrict__ u2p, const int* __restrict__ ridx, u16* __restrict__ z2s, int k)
{
  const int t = threadIdx.x, wid = t >> 6, l = t & 63;
  const int n = blockIdx.x * 4 + wid;
  float s = 0.f;
#pragma unroll
  for (int sp = 0; sp < 16; ++sp) s += u2p[(size_t)sp * 262144 + (size_t)n * 64 + l];
  int e = ridx[n * 2 + k];
  float v = ((l >> 3) == e) ? 2.0f * s : 0.0f;   // SCALING folded
  z2s[(size_t)n * 64 + l] = f2bf(v);
}

// ---------------- fc2 GEMM + lora + weighted accumulate -> out ----------------
__global__ __launch_bounds__(256) void gemm_fc2_k(
    const u16* __restrict__ h, const u16* __restrict__ W2b,
    const u16* __restrict__ B2c, const u16* __restrict__ z2s,
    const float* __restrict__ b2, const float* __restrict__ rw,
    float* __restrict__ out, int kI, int addF)
{
  __shared__ __align__(16) short lds[24576];
  short* As = lds;           // [128][32]
  short* Bs = lds + 4096;    // [128][32]
  short* Bl = lds + 8192;    // [128][64]
  short* Zs = lds + 16384;   // [128][64]
  const int t = threadIdx.x, l = t & 63, wid = t >> 6;
  const int wr = wid >> 1, wc = wid & 1;
  const int fq = l >> 4, fr = l & 15;
  const int brow = blockIdx.y * 128, bcol = blockIdx.x * 128;

#pragma unroll
  for (int p = 0; p < 4; ++p){
    int i = p * 256 + t, row = i >> 3, ch = i & 7;
    GLD(B2c + (size_t)(bcol + row) * 64 + ch * 8, (char*)Bl + i * 16);
    GLD(z2s + (size_t)(brow + row) * 64 + ch * 8, (char*)Zs + i * 16);
  }

  f32x4 acc[4][4] = {};
  for (int kt = 0; kt < 256; ++kt){
    const int k0 = kt * 32;
#pragma unroll
    for (int p = 0; p < 2; ++p){
      int i = p * 256 + t, row = i >> 2, ch = i & 3;
      GLD(h   + (size_t)(brow + row) * 8192 + k0 + ch * 8, (char*)As + i * 16);
      GLD(W2b + (size_t)(bcol + row) * 8192 + k0 + ch * 8, (char*)Bs + i * 16);
    }
    __syncthreads();
    short8 a[4], b[4];
#pragma unroll
    for (int m = 0; m < 4; ++m) a[m] = *(const short8*)&As[(wr * 64 + m * 16 + fr) * 32 + fq * 8];
#pragma unroll
    for (int n = 0; n < 4; ++n) b[n] = *(const short8*)&Bs[(wc * 64 + n * 16 + fr) * 32 + fq * 8];
#pragma unroll
    for (int m = 0; m < 4; ++m)
#pragma unroll
      for (int n = 0; n < 4; ++n)
        acc[m][n] = __builtin_amdgcn_mfma_f32_16x16x32_bf16(a[m], b[n], acc[m][n], 0, 0, 0);
    __syncthreads();
  }
#pragma unroll
  for (int kk = 0; kk < 2; ++kk){
    short8 za[4], zb[4];
#pragma unroll
    for (int m = 0; m < 4; ++m) za[m] = *(const short8*)&Zs[(wr * 64 + m * 16 + fr) * 64 + kk * 32 + fq * 8];
#pragma unroll
    for (int n = 0; n < 4; ++n) zb[n] = *(const short8*)&Bl[(wc * 64 + n * 16 + fr) * 64 + kk * 32 + fq * 8];
#pragma unroll
    for (int m = 0; m < 4; ++m)
#pragma unroll
      for (int n = 0; n < 4; ++n)
        acc[m][n] = __builtin_amdgcn_mfma_f32_16x16x32_bf16(za[m], zb[n], acc[m][n], 0, 0, 0);
  }
#pragma unroll
  for (int n = 0; n < 4; ++n){
    int gcol = bcol + wc * 64 + n * 16 + fr;
    float bv = b2[gcol];
#pragma unroll
    for (int m = 0; m < 4; ++m)
#pragma unroll
      for (int j = 0; j < 4; ++j){
        int grow = brow + wr * 64 + m * 16 + fq * 4 + j;
        float wk = rw[grow * 2 + kI];
        float v = wk * (acc[m][n][j] + bv);
        float* po = out + (size_t)grow * 2048 + gcol;
        if (addF) v += *po;
        *po = v;
      }
  }
}

// ---------------- launch ----------------
extern "C" void kernel_launch(void* const* d_in, const int* in_sizes, int n_in,
                              void* d_out, int out_size, void* d_ws, size_t ws_size,
                              hipStream_t stream) {
  const float* x  = (const float*)d_in[0];
  const float* Wr = (const float*)d_in[1];
  const float* br = (const float*)d_in[2];
  const float* W1 = (const float*)d_in[3];
  const float* b1 = (const float*)d_in[4];
  const float* W2 = (const float*)d_in[5];
  const float* b2 = (const float*)d_in[6];
  const float* A1 = (const float*)d_in[7];
  const float* B1 = (const float*)d_in[8];
  const float* A2 = (const float*)d_in[9];
  const float* B2 = (const float*)d_in[10];
  float* out = (float*)d_out;

  char* ws = (char*)d_ws;
  u16*   xb   = (u16*)  (ws);                        // 16 MB
  u16*   W1b  = (u16*)  (ws + ((size_t)16 << 20));   // 32 MB
  u16*   W2b  = (u16*)  (ws + ((size_t)48 << 20));   // 32 MB
  u16*   A2b  = (u16*)  (ws + ((size_t)80 << 20));   // 1 MB
  u16*   B1c  = (u16*)  (ws + ((size_t)81 << 20));   // 1 MB
  u16*   B2c  = (u16*)  (ws + ((size_t)82 << 20));   // 0.25 MB
  u16*   z1s0 = (u16*)  (ws + ((size_t)83 << 20));   // 0.5 MB
  u16*   z1d  = (u16*)  (ws + ((size_t)84 << 20));   // 0.5 MB
  u16*   z2s  = (u16*)  (ws + ((size_t)85 << 20));   // 0.5 MB
  float* rw   = (float*)(ws + ((size_t)86 << 20));   // 32 KB
  int*   ridx = (int*)  (ws + ((size_t)87 << 20));   // 32 KB
  u16*   h0   = (u16*)  (ws + ((size_t)88 << 20));   // 64 MB
  u16*   h1   = (u16*)  (ws + ((size_t)152 << 20));  // 64 MB
  float* u2p  = (float*)(ws + ((size_t)216 << 20));  // 16 MB  (total 232 MB)

  cast_flat_k<<<2048, 256, 0, stream>>>(W1, W1b, 16777216 / 4);
  cast_flat_k<<<2048, 256, 0, stream>>>(W2, W2b, 16777216 / 4);
  cast_flat_k<<<512,  256, 0, stream>>>(A2, A2b, 524288 / 4);
  cast_b1c_k<<<2048, 256, 0, stream>>>(B1, B1c);
  cast_b2c_k<<<512,  256, 0, stream>>>(B2, B2c);

  router_k<<<1024, 256, 0, stream>>>(x, Wr, br, A1, xb, z1s0, z1d, rw, ridx);

  gemm_fc1_k<<<dim3(64, 32), 256, 0, stream>>>(xb, W1b, B1c, z1s0, z1d, b1, h0, h1);

  // k = 0
  gemm_u2_k<<<dim3(16, 32), 256, 0, stream>>>(h0, A2b, u2p);
  zbuild_k<<<1024, 256, 0, stream>>>(u2p, ridx, z2s, 0);
  gemm_fc2_k<<<dim3(16, 32), 256, 0, stream>>>(h0, W2b, B2c, z2s, b2, rw, out, 0, 0);
  // k = 1
  gemm_u2_k<<<dim3(16, 32), 256, 0, stream>>>(h1, A2b, u2p);
  zbuild_k<<<1024, 256, 0, stream>>>(u2p, ridx, z2s, 1);
  gemm_fc2_k<<<dim3(16, 32), 256, 0, stream>>>(h1, W2b, B2c, z2s, b2, rw, out, 1, 1);
}

// Round 3
// 918.325 us; speedup vs baseline: 1.0211x; 1.0211x over previous
//
#include <hip/hip_runtime.h>

typedef __attribute__((ext_vector_type(4))) float f32x4;
typedef __attribute__((ext_vector_type(8))) short short8;
typedef __attribute__((ext_vector_type(4))) unsigned short u16x4;
typedef unsigned short u16;

#define GLD(g, l) __builtin_amdgcn_global_load_lds((const __attribute__((address_space(1))) unsigned int*)(g), (__attribute__((address_space(3))) unsigned int*)(l), 16, 0, 0)

__device__ __forceinline__ u16 f2bf(float f){
  union { float f; unsigned u; } c; c.f = f;
  unsigned r = c.u + 0x7FFFu + ((c.u >> 16) & 1u);
  return (u16)(r >> 16);
}

__device__ __forceinline__ float gelu_tanh(float x){
  float a = 0.7978845608028654f * (x + 0.044715f * x * x * x);
  float t = 1.0f - 2.0f / (__expf(2.0f * a) + 1.0f);
  return 0.5f * x * (1.0f + t);
}

// ---------------- cast kernels ----------------
__global__ __launch_bounds__(256) void cast_flat_k(const float* __restrict__ s, u16* __restrict__ d, int n4){
  int i = blockIdx.x * 256 + threadIdx.x;
  int str = gridDim.x * 256;
  for (; i < n4; i += str){
    f32x4 v = ((const f32x4*)s)[i];
    u16x4 o; o[0]=f2bf(v[0]); o[1]=f2bf(v[1]); o[2]=f2bf(v[2]); o[3]=f2bf(v[3]);
    ((u16x4*)d)[i] = o;
  }
}

// B1 [E=8, F=8192, R=8] -> B1c [F, 64]: B1c[f][e*8+r] = B1[e][f][r]
__global__ __launch_bounds__(256) void cast_b1c_k(const float* __restrict__ B1, u16* __restrict__ B1c){
  int i = blockIdx.x * 256 + threadIdx.x;   // 0..524287
  int f = i >> 6, er = i & 63, e = er >> 3, r = er & 7;
  B1c[i] = f2bf(B1[(size_t)e * 65536 + (size_t)f * 8 + r]);
}

// B2 [E=8, D=2048, R=8] -> B2c [D, 64]: B2c[d][e*8+r] = B2[e][d][r]
__global__ __launch_bounds__(256) void cast_b2c_k(const float* __restrict__ B2, u16* __restrict__ B2c){
  int i = blockIdx.x * 256 + threadIdx.x;   // 0..131071
  int d_ = i >> 6, er = i & 63, e = er >> 3, r = er & 7;
  B2c[i] = f2bf(B2[(size_t)e * 16384 + (size_t)d_ * 8 + r]);
}

// ---------------- router (+ x cast + selected u1 -> z1) ----------------
__global__ __launch_bounds__(256) void router_k(
    const float* __restrict__ x, const float* __restrict__ Wr, const float* __restrict__ br,
    const float* __restrict__ A1, u16* __restrict__ xb,
    u16* __restrict__ z1s0, u16* __restrict__ z1d,
    float* __restrict__ rw, int* __restrict__ ridx)
{
  const int t = threadIdx.x, wid = t >> 6, l = t & 63;
  const int n = blockIdx.x * 4 + wid;
  const float* xr = x + (size_t)n * 2048;
  f32x4 xv[8];
#pragma unroll
  for (int i = 0; i < 8; ++i) xv[i] = *(const f32x4*)(xr + i * 256 + l * 4);
#pragma unroll
  for (int i = 0; i < 8; ++i){
    u16x4 o; o[0]=f2bf(xv[i][0]); o[1]=f2bf(xv[i][1]); o[2]=f2bf(xv[i][2]); o[3]=f2bf(xv[i][3]);
    *(u16x4*)(xb + (size_t)n * 2048 + i * 256 + l * 4) = o;
  }
  float p[8];
#pragma unroll
  for (int e = 0; e < 8; ++e){
    const float* wrow = Wr + (size_t)e * 2048;
    float s = 0.f;
#pragma unroll
    for (int i = 0; i < 8; ++i){
      f32x4 wv = *(const f32x4*)(wrow + i * 256 + l * 4);
      s += xv[i][0]*wv[0] + xv[i][1]*wv[1] + xv[i][2]*wv[2] + xv[i][3]*wv[3];
    }
#pragma unroll
    for (int off = 32; off; off >>= 1) s += __shfl_xor(s, off, 64);
    p[e] = s + br[e];
  }
  float mx = p[0];
#pragma unroll
  for (int e = 1; e < 8; ++e) mx = fmaxf(mx, p[e]);
  float den = 0.f;
#pragma unroll
  for (int e = 0; e < 8; ++e){ p[e] = __expf(p[e] - mx); den += p[e]; }
  float inv = 1.f / den;
#pragma unroll
  for (int e = 0; e < 8; ++e) p[e] *= inv;
  int e0 = 0; float p0 = p[0];
#pragma unroll
  for (int e = 1; e < 8; ++e){ if (p[e] > p0){ p0 = p[e]; e0 = e; } }
  int e1 = (e0 == 0) ? 1 : 0; float p1 = p[(e0 == 0) ? 1 : 0];
#pragma unroll
  for (int e = 0; e < 8; ++e){ if (e != e0 && p[e] > p1){ p1 = p[e]; e1 = e; } }

  float mz0 = 0.f, mz1 = 0.f;
#pragma unroll
  for (int r = 0; r < 8; ++r){
    const float* a1r = A1 + ((size_t)(e0 * 8 + r)) * 2048;
    float s = 0.f;
#pragma unroll
    for (int i = 0; i < 8; ++i){
      f32x4 av = *(const f32x4*)(a1r + i * 256 + l * 4);
      s += xv[i][0]*av[0] + xv[i][1]*av[1] + xv[i][2]*av[2] + xv[i][3]*av[3];
    }
#pragma unroll
    for (int off = 32; off; off >>= 1) s += __shfl_xor(s, off, 64);
    if (l == e0 * 8 + r) mz0 = 2.0f * s;   // SCALING folded
  }
#pragma unroll
  for (int r = 0; r < 8; ++r){
    const float* a1r = A1 + ((size_t)(e1 * 8 + r)) * 2048;
    float s = 0.f;
#pragma unroll
    for (int i = 0; i < 8; ++i){
      f32x4 av = *(const f32x4*)(a1r + i * 256 + l * 4);
      s += xv[i][0]*av[0] + xv[i][1]*av[1] + xv[i][2]*av[2] + xv[i][3]*av[3];
    }
#pragma unroll
    for (int off = 32; off; off >>= 1) s += __shfl_xor(s, off, 64);
    if (l == e1 * 8 + r) mz1 = 2.0f * s;
  }
  z1s0[(size_t)n * 64 + l] = f2bf(mz0);
  z1d [(size_t)n * 64 + l] = f2bf(mz1 - mz0);
  if (l == 0){
    rw[n * 2 + 0] = p0; rw[n * 2 + 1] = p1;
    ridx[n * 2 + 0] = e0; ridx[n * 2 + 1] = e1;
  }
}

// ---------------- fc1 GEMM + lora + gelu -> h0, h1 (contiguous as h[8192][8192]) ----------------
__global__ __launch_bounds__(256) void gemm_fc1_k(
    const u16* __restrict__ xb, const u16* __restrict__ W1b,
    const u16* __restrict__ B1c, const u16* __restrict__ z1s0, const u16* __restrict__ z1d,
    const float* __restrict__ b1, u16* __restrict__ h0, u16* __restrict__ h1)
{
  __shared__ __align__(16) short lds[24576];
  short* As = lds;           // [128][32]
  short* Bs = lds + 4096;    // [128][32]
  short* Bl = lds + 8192;    // [128][64]
  short* Zs = lds + 16384;   // [128][64]
  const int t = threadIdx.x, l = t & 63, wid = t >> 6;
  const int wr = wid >> 1, wc = wid & 1;
  const int fq = l >> 4, fr = l & 15;
  const int brow = blockIdx.y * 128, bcol = blockIdx.x * 128;

#pragma unroll
  for (int p = 0; p < 4; ++p){
    int i = p * 256 + t, row = i >> 3, ch = i & 7;
    GLD(B1c + (size_t)(bcol + row) * 64 + ch * 8, (char*)Bl + i * 16);
    GLD(z1s0 + (size_t)(brow + row) * 64 + ch * 8, (char*)Zs + i * 16);
  }

  f32x4 acc[4][4] = {};
  for (int kt = 0; kt < 64; ++kt){
    const int k0 = kt * 32;
#pragma unroll
    for (int p = 0; p < 2; ++p){
      int i = p * 256 + t, row = i >> 2, ch = i & 3;
      GLD(xb  + (size_t)(brow + row) * 2048 + k0 + ch * 8, (char*)As + i * 16);
      GLD(W1b + (size_t)(bcol + row) * 2048 + k0 + ch * 8, (char*)Bs + i * 16);
    }
    __syncthreads();
    short8 a[4], b[4];
#pragma unroll
    for (int m = 0; m < 4; ++m) a[m] = *(const short8*)&As[(wr * 64 + m * 16 + fr) * 32 + fq * 8];
#pragma unroll
    for (int n = 0; n < 4; ++n) b[n] = *(const short8*)&Bs[(wc * 64 + n * 16 + fr) * 32 + fq * 8];
#pragma unroll
    for (int m = 0; m < 4; ++m)
#pragma unroll
      for (int n = 0; n < 4; ++n)
        acc[m][n] = __builtin_amdgcn_mfma_f32_16x16x32_bf16(a[m], b[n], acc[m][n], 0, 0, 0);
    __syncthreads();
  }

#pragma unroll
  for (int n = 0; n < 4; ++n){
    float bv = b1[bcol + wc * 64 + n * 16 + fr];
#pragma unroll
    for (int m = 0; m < 4; ++m)
#pragma unroll
      for (int j = 0; j < 4; ++j) acc[m][n][j] += bv;
  }
  // lora for k=0 (Zs holds z1s0); K=64 contraction in two K=32 steps
#pragma unroll
  for (int kk = 0; kk < 2; ++kk){
    short8 za[4], zb[4];
#pragma unroll
    for (int m = 0; m < 4; ++m) za[m] = *(const short8*)&Zs[(wr * 64 + m * 16 + fr) * 64 + kk * 32 + fq * 8];
#pragma unroll
    for (int n = 0; n < 4; ++n) zb[n] = *(const short8*)&Bl[(wc * 64 + n * 16 + fr) * 64 + kk * 32 + fq * 8];
#pragma unroll
    for (int m = 0; m < 4; ++m)
#pragma unroll
      for (int n = 0; n < 4; ++n)
        acc[m][n] = __builtin_amdgcn_mfma_f32_16x16x32_bf16(za[m], zb[n], acc[m][n], 0, 0, 0);
  }
#pragma unroll
  for (int m = 0; m < 4; ++m)
#pragma unroll
    for (int n = 0; n < 4; ++n)
#pragma unroll
      for (int j = 0; j < 4; ++j){
        int grow = brow + wr * 64 + m * 16 + fq * 4 + j;
        int gcol = bcol + wc * 64 + n * 16 + fr;
        h0[(size_t)grow * 8192 + gcol] = f2bf(gelu_tanh(acc[m][n][j]));
      }
  __syncthreads();
  // restage Zs with z1d = z1(k=1) - z1(k=0); acc += z1d@B1 gives k=1 state
#pragma unroll
  for (int p = 0; p < 4; ++p){
    int i = p * 256 + t, row = i >> 3, ch = i & 7;
    GLD(z1d + (size_t)(brow + row) * 64 + ch * 8, (char*)Zs + i * 16);
  }
  __syncthreads();
#pragma unroll
  for (int kk = 0; kk < 2; ++kk){
    short8 za[4], zb[4];
#pragma unroll
    for (int m = 0; m < 4; ++m) za[m] = *(const short8*)&Zs[(wr * 64 + m * 16 + fr) * 64 + kk * 32 + fq * 8];
#pragma unroll
    for (int n = 0; n < 4; ++n) zb[n] = *(const short8*)&Bl[(wc * 64 + n * 16 + fr) * 64 + kk * 32 + fq * 8];
#pragma unroll
    for (int m = 0; m < 4; ++m)
#pragma unroll
      for (int n = 0; n < 4; ++n)
        acc[m][n] = __builtin_amdgcn_mfma_f32_16x16x32_bf16(za[m], zb[n], acc[m][n], 0, 0, 0);
  }
#pragma unroll
  for (int m = 0; m < 4; ++m)
#pragma unroll
    for (int n = 0; n < 4; ++n)
#pragma unroll
      for (int j = 0; j < 4; ++j){
        int grow = brow + wr * 64 + m * 16 + fq * 4 + j;
        int gcol = bcol + wc * 64 + n * 16 + fr;
        h1[(size_t)grow * 8192 + gcol] = f2bf(gelu_tanh(acc[m][n][j]));
      }
}

// ---------------- u2 = h_cat @ A2_flat^T over virtual M=8192, split-K 16 ----------------
__global__ __launch_bounds__(256) void gemm_u2_k(
    const u16* __restrict__ h, const u16* __restrict__ A2b, float* __restrict__ u2p)
{
  __shared__ __align__(16) short lds[6144];
  short* As = lds;          // [128][32]
  short* Bs = lds + 4096;   // [64][32]
  const int t = threadIdx.x, l = t & 63, wid = t >> 6;
  const int fq = l >> 4, fr = l & 15;
  const int bs = blockIdx.x;            // split 0..15
  const int brow = blockIdx.y * 128;    // 0..8064
  const int kb = bs * 512;

  f32x4 acc[2][4] = {};
  for (int kt = 0; kt < 16; ++kt){
    const int k0 = kb + kt * 32;
#pragma unroll
    for (int p = 0; p < 2; ++p){
      int i = p * 256 + t, row = i >> 2, ch = i & 3;
      GLD(h + (size_t)(brow + row) * 8192 + k0 + ch * 8, (char*)As + i * 16);
    }
    { int i = t, row = i >> 2, ch = i & 3;
      GLD(A2b + (size_t)row * 8192 + k0 + ch * 8, (char*)Bs + i * 16); }
    __syncthreads();
    short8 a[2], b[4];
#pragma unroll
    for (int m = 0; m < 2; ++m) a[m] = *(const short8*)&As[(wid * 32 + m * 16 + fr) * 32 + fq * 8];
#pragma unroll
    for (int n = 0; n < 4; ++n) b[n] = *(const short8*)&Bs[(n * 16 + fr) * 32 + fq * 8];
#pragma unroll
    for (int m = 0; m < 2; ++m)
#pragma unroll
      for (int n = 0; n < 4; ++n)
        acc[m][n] = __builtin_amdgcn_mfma_f32_16x16x32_bf16(a[m], b[n], acc[m][n], 0, 0, 0);
    __syncthreads();
  }
#pragma unroll
  for (int m = 0; m < 2; ++m)
#pragma unroll
    for (int n = 0; n < 4; ++n)
#pragma unroll
      for (int j = 0; j < 4; ++j){
        int grow = brow + wid * 32 + m * 16 + fq * 4 + j;
        u2p[(size_t)bs * 524288 + (size_t)grow * 64 + n * 16 + fr] = acc[m][n][j];
      }
}

// ---------------- z2 build over both k: z2s[8192][64] ----------------
__global__ __launch_bounds__(256) void zbuild_k(
    const float* __restrict__ u2p, const int* __restrict__ ridx, u16* __restrict__ z2s)
{
  const int t = threadIdx.x, wid = t >> 6, l = t & 63;
  const int n = blockIdx.x * 4 + wid;   // 0..8191
  float s = 0.f;
#pragma unroll
  for (int sp = 0; sp < 16; ++sp) s += u2p[(size_t)sp * 524288 + (size_t)n * 64 + l];
  int nn = (n < 4096) ? n : n - 4096;
  int k = (n < 4096) ? 0 : 1;
  int e = ridx[nn * 2 + k];
  float v = ((l >> 3) == e) ? 2.0f * s : 0.0f;   // SCALING folded
  z2s[(size_t)n * 64 + l] = f2bf(v);
}

// ---------------- fc2 pair GEMM: both k share W2 B-panel; direct out write ----------------
__global__ __launch_bounds__(256, 2) void gemm_fc2_pair(
    const u16* __restrict__ h, const u16* __restrict__ W2b,
    const u16* __restrict__ B2c, const u16* __restrict__ z2s,
    const float* __restrict__ b2, const float* __restrict__ rw,
    float* __restrict__ out)
{
  __shared__ __align__(16) short lds[12288];
  short* As0 = lds;           // [128][32] rows of h0
  short* As1 = lds + 4096;    // [128][32] rows of h1
  short* Bs  = lds + 8192;    // [128][32] W2 cols
  const int t = threadIdx.x, l = t & 63, wid = t >> 6;
  const int wr = wid >> 1, wc = wid & 1;
  const int fq = l >> 4, fr = l & 15;
  const int brow = blockIdx.y * 128, bcol = blockIdx.x * 128;

  f32x4 acc0[4][4] = {};
  f32x4 acc1[4][4] = {};
  for (int kt = 0; kt < 256; ++kt){
    const int k0 = kt * 32;
#pragma unroll
    for (int p = 0; p < 2; ++p){
      int i = p * 256 + t, row = i >> 2, ch = i & 3;
      GLD(h   + (size_t)(brow + row) * 8192 + k0 + ch * 8,        (char*)As0 + i * 16);
      GLD(h   + (size_t)(4096 + brow + row) * 8192 + k0 + ch * 8, (char*)As1 + i * 16);
      GLD(W2b + (size_t)(bcol + row) * 8192 + k0 + ch * 8,        (char*)Bs  + i * 16);
    }
    __syncthreads();
    short8 a0[4], a1[4], b[4];
#pragma unroll
    for (int m = 0; m < 4; ++m) a0[m] = *(const short8*)&As0[(wr * 64 + m * 16 + fr) * 32 + fq * 8];
#pragma unroll
    for (int m = 0; m < 4; ++m) a1[m] = *(const short8*)&As1[(wr * 64 + m * 16 + fr) * 32 + fq * 8];
#pragma unroll
    for (int n = 0; n < 4; ++n) b[n] = *(const short8*)&Bs[(wc * 64 + n * 16 + fr) * 32 + fq * 8];
#pragma unroll
    for (int m = 0; m < 4; ++m)
#pragma unroll
      for (int n = 0; n < 4; ++n){
        acc0[m][n] = __builtin_amdgcn_mfma_f32_16x16x32_bf16(a0[m], b[n], acc0[m][n], 0, 0, 0);
        acc1[m][n] = __builtin_amdgcn_mfma_f32_16x16x32_bf16(a1[m], b[n], acc1[m][n], 0, 0, 0);
      }
    __syncthreads();
  }
  // LoRA: acc_k += z2s_k rows @ B2c cols (K=64 in two 32-steps); direct global frag loads
#pragma unroll
  for (int kk = 0; kk < 2; ++kk){
    short8 za0[4], za1[4], zb[4];
#pragma unroll
    for (int m = 0; m < 4; ++m){
      za0[m] = *(const short8*)&z2s[(size_t)(brow + wr * 64 + m * 16 + fr) * 64 + kk * 32 + fq * 8];
      za1[m] = *(const short8*)&z2s[(size_t)(4096 + brow + wr * 64 + m * 16 + fr) * 64 + kk * 32 + fq * 8];
    }
#pragma unroll
    for (int n = 0; n < 4; ++n) zb[n] = *(const short8*)&B2c[(size_t)(bcol + wc * 64 + n * 16 + fr) * 64 + kk * 32 + fq * 8];
#pragma unroll
    for (int m = 0; m < 4; ++m)
#pragma unroll
      for (int n = 0; n < 4; ++n){
        acc0[m][n] = __builtin_amdgcn_mfma_f32_16x16x32_bf16(za0[m], zb[n], acc0[m][n], 0, 0, 0);
        acc1[m][n] = __builtin_amdgcn_mfma_f32_16x16x32_bf16(za1[m], zb[n], acc1[m][n], 0, 0, 0);
      }
  }
#pragma unroll
  for (int n = 0; n < 4; ++n){
    int gcol = bcol + wc * 64 + n * 16 + fr;
    float bv = b2[gcol];
#pragma unroll
    for (int m = 0; m < 4; ++m)
#pragma unroll
      for (int j = 0; j < 4; ++j){
        int grow = brow + wr * 64 + m * 16 + fq * 4 + j;
        float w0 = rw[grow * 2 + 0], w1 = rw[grow * 2 + 1];
        out[(size_t)grow * 2048 + gcol] = w0 * (acc0[m][n][j] + bv) + w1 * (acc1[m][n][j] + bv);
      }
  }
}

// ---------------- launch ----------------
extern "C" void kernel_launch(void* const* d_in, const int* in_sizes, int n_in,
                              void* d_out, int out_size, void* d_ws, size_t ws_size,
                              hipStream_t stream) {
  const float* x  = (const float*)d_in[0];
  const float* Wr = (const float*)d_in[1];
  const float* br = (const float*)d_in[2];
  const float* W1 = (const float*)d_in[3];
  const float* b1 = (const float*)d_in[4];
  const float* W2 = (const float*)d_in[5];
  const float* b2 = (const float*)d_in[6];
  const float* A1 = (const float*)d_in[7];
  const float* B1 = (const float*)d_in[8];
  const float* A2 = (const float*)d_in[9];
  const float* B2 = (const float*)d_in[10];
  float* out = (float*)d_out;

  char* ws = (char*)d_ws;
  // u2p (32 MB) overlaps xb+W1b[0:16MB] — both dead before gemm_u2_k runs.
  float* u2p  = (float*)(ws);                        // 32 MB (after fc1)
  u16*   xb   = (u16*)  (ws);                        // 16 MB (until fc1)
  u16*   W1b  = (u16*)  (ws + ((size_t)16 << 20));   // 32 MB (until fc1)
  u16*   W2b  = (u16*)  (ws + ((size_t)48 << 20));   // 32 MB
  u16*   A2b  = (u16*)  (ws + ((size_t)80 << 20));   // 1 MB
  u16*   B1c  = (u16*)  (ws + ((size_t)81 << 20));   // 1 MB
  u16*   B2c  = (u16*)  (ws + ((size_t)82 << 20));   // 0.25 MB
  u16*   z1s0 = (u16*)  (ws + ((size_t)83 << 20));   // 0.5 MB
  u16*   z1d  = (u16*)  (ws + ((size_t)84 << 20));   // 0.5 MB
  u16*   z2s  = (u16*)  (ws + ((size_t)85 << 20));   // 1 MB [8192][64]
  float* rw   = (float*)(ws + ((size_t)86 << 20));   // 32 KB
  int*   ridx = (int*)  (ws + ((size_t)87 << 20));   // 32 KB
  u16*   h0   = (u16*)  (ws + ((size_t)88 << 20));   // 64 MB  \ contiguous h[8192][8192]
  u16*   h1   = (u16*)  (ws + ((size_t)152 << 20));  // 64 MB  /

  cast_flat_k<<<2048, 256, 0, stream>>>(W1, W1b, 16777216 / 4);
  cast_flat_k<<<2048, 256, 0, stream>>>(W2, W2b, 16777216 / 4);
  cast_flat_k<<<512,  256, 0, stream>>>(A2, A2b, 524288 / 4);
  cast_b1c_k<<<2048, 256, 0, stream>>>(B1, B1c);
  cast_b2c_k<<<512,  256, 0, stream>>>(B2, B2c);

  router_k<<<1024, 256, 0, stream>>>(x, Wr, br, A1, xb, z1s0, z1d, rw, ridx);

  gemm_fc1_k<<<dim3(64, 32), 256, 0, stream>>>(xb, W1b, B1c, z1s0, z1d, b1, h0, h1);

  gemm_u2_k<<<dim3(16, 64), 256, 0, stream>>>(h0, A2b, u2p);
  zbuild_k<<<2048, 256, 0, stream>>>(u2p, ridx, z2s);
  gemm_fc2_pair<<<dim3(16, 32), 256, 0, stream>>>(h0, W2b, B2c, z2s, b2, rw, out);
}